// Round 12
// baseline (5315.442 us; speedup 1.0000x reference)
//
#include <hip/hip_runtime.h>

#define FPS_N 32768
#define FPS_M 2048
#define FPS_B 16
#define BLK_PER_B 4
#define FPS_T 1024                // 16 waves; wave 0 dual-role (scan + comm)
#define PTS (FPS_N / BLK_PER_B)   // 8192 points per block
#define PPT (PTS / FPS_T)         // 8 points per thread
#define NWAVE (FPS_T / 64)        // 16 waves

typedef unsigned long long ull;

// FPS, 4 blocks/batch (64 blocks, cooperative). Round-9 protocol restored
// (best known: single-word publish, shfl reduces, coord fetch from immutable
// input, outb AFTER release) -- round 10/11 regressions were: s_sleep on the
// path (+320cyc/step), outb global store before the workgroup-release (vmcnt
// drain on the release), DPP no faster than shfl.
// Round-12 change: HALVE CONSENSUS PARTICIPANTS (8 -> 4 publishers/batch).
// 1024 threads, 8192 pts in 128 KiB LDS (float4), dist 8 VGPR/thread.
// Straggler spread and poll-line occupancy both shrink; under round-robin
// dispatch batch b's blocks {b,b+16,b+32,b+48} share XCD b%8 (heuristic).
// Wave 0 dual-role: scans its slice, keeps its partial in-register, gathers
// waves 1-15 partials from LDS (trickle-in), publishes 1 relaxed agent word:
//   w = dist<<32 | (32767-gidx)<<17 | tag    (tag = s, 12 bits)
// u64-max == np.argmax first-occurrence (dist>=0 -> IEEE-bit monotone;
// inverted index -> lowest-index ties). Polls 4 slots (one 64-B line,
// parity double-buffered: slot reuse at s+2 is provably post-consumption;
// ws 0xAA poison -> tag field 0xAAA=2730 never matches tags <= 2047).
// Winner coords: lanes 0-2 load X/Y/Z[widx] (L2-resident immutable input),
// wave 0 shares via 3 shfls; lanes 0-2 post to LDS; lane 0 releases swtag
// (lgkmcnt drain orders the coord ds_writes); outb written after release.
// Numerics bit-exact vs numpy: contract off, (dx*dx+dy*dy)+dz*dz, no fma.
__global__ __launch_bounds__(FPS_T) void fps_kernel(const float* __restrict__ pts,
                                                    float* __restrict__ out,
                                                    ull* __restrict__ ws) {
#pragma clang fp contract(off)
    __shared__ float4 sc[PTS];          // 128 KiB coords
    __shared__ ull part[NWAVE];         // tagged per-wave partials (1-15 used)
    __shared__ float swx, swy, swz;     // winner coords
    __shared__ unsigned swtag;          // winner tag (release/acquire)

    const int blk = blockIdx.x;
    const int b = blk & 15;             // batch; 4 blocks/batch share XCD blk%8
    const int j = blk >> 4;             // block-within-batch 0..3
    const int tid = threadIdx.x;
    const int wv = tid >> 6;
    const int lane = tid & 63;
    const float* __restrict__ X = pts + (size_t)b * 3 * FPS_N;
    const float* __restrict__ Y = X + FPS_N;
    const float* __restrict__ Z = Y + FPS_N;
    const int off = j * PTS;
    float* __restrict__ outb = out + (size_t)b * 3 * FPS_M;
    ull* __restrict__ wsb = ws + (size_t)b * 16;  // 2 parities x 8 words (2 lines)

    for (int q = tid; q < PTS; q += FPS_T)        // one-time coord stage
        sc[q] = make_float4(X[off + q], Y[off + q], Z[off + q], 0.0f);
    if (tid < NWAVE) part[tid] = 0;               // kill stale-tag aliasing
    if (tid == NWAVE) swtag = 0;
    __syncthreads();                              // only barrier (pre-loop)

    float dist[PPT];
#pragma unroll
    for (int k = 0; k < PPT; ++k) dist[k] = 1e10f;
    float lx = X[0], ly = Y[0], lz = Z[0];        // first selection = index 0

    if (j == 0 && tid == 0) {                     // emit selection 0
        outb[0]         = lx;
        outb[FPS_M]     = ly;
        outb[2 * FPS_M] = lz;
    }

    for (int s = 1; s < FPS_M; ++s) {
        const unsigned tag = (unsigned)s;

        // ---- every wave: scan own points, pack, 6-shfl u64-max ----
        float bd = -1.0f;
        int bi = 0;
#pragma unroll
        for (int k = 0; k < PPT; ++k) {
            const int q = k * FPS_T + tid;
            float4 c = sc[q];                            // ds_read_b128
            float dx = c.x - lx, dy = c.y - ly, dz = c.z - lz;
            float d = (dx * dx + dy * dy) + dz * dz;     // numpy order, no fma
            float nd = d < dist[k] ? d : dist[k];
            dist[k] = nd;
            if (nd > bd) { bd = nd; bi = q; }            // strict >: lowest idx
        }
        ull w = ((ull)__float_as_uint(bd) << 32)
              | ((ull)(32767u - (unsigned)(off + bi)) << 17)
              | (ull)tag;
#pragma unroll
        for (int o = 32; o > 0; o >>= 1) {               // wave max -> lane 0
            ull ow = __shfl_down(w, o);
            if (ow > w) w = ow;
        }

        if (wv != 0) {
            // ---- scan waves: post partial, wait for winner ----
            if (lane == 0)
                __hip_atomic_store(&part[wv], w, __ATOMIC_RELAXED,
                                   __HIP_MEMORY_SCOPE_WORKGROUP);
            for (int it = 0; it < (1 << 25); ++it) {     // LDS broadcast spin
                unsigned t = __hip_atomic_load(&swtag, __ATOMIC_ACQUIRE,
                                               __HIP_MEMORY_SCOPE_WORKGROUP);
                if (t == tag) break;
            }
            lx = swx;
            ly = swy;
            lz = swz;
        } else {
            // ---- wave 0: gather 15 partials (trickle-in) + own ----
            ull pv = (lane == 0) ? w : 0;
            bool ok = (lane == 0) || (lane >= NWAVE);
            for (int it = 0; it < (1 << 25); ++it) {
                if (!ok) {
                    pv = __hip_atomic_load(&part[lane], __ATOMIC_RELAXED,
                                           __HIP_MEMORY_SCOPE_WORKGROUP);
                    ok = ((unsigned)(pv & 0xFFFull) == tag);
                }
                if (__all(ok)) break;
            }
#pragma unroll
            for (int o = 8; o > 0; o >>= 1) {            // block max -> lane 0
                ull ov = __shfl_down(pv, o);
                if (ov > pv) pv = ov;
            }
            ull* line = wsb + (s & 1) * 8;               // parity 64-B line
            if (lane == 0)                               // publish 1 word
                __hip_atomic_store(line + j, pv, __ATOMIC_RELAXED,
                                   __HIP_MEMORY_SCOPE_AGENT);
            // poll 4 slots (lanes 0-3), relaxed, self-throttled
            ull r = 0;
            ok = (lane >= BLK_PER_B);
            for (int it = 0; it < (1 << 25); ++it) {
                if (!ok) {
                    r = __hip_atomic_load(line + lane, __ATOMIC_RELAXED,
                                          __HIP_MEMORY_SCOPE_AGENT);
                    ok = ((unsigned)(r & 0xFFFull) == tag);
                }
                if (__all(ok)) break;
            }
            if (lane >= BLK_PER_B) r = 0;
#pragma unroll
            for (int o = 2; o > 0; o >>= 1) {            // winner -> lane 0
                ull orr = __shfl_down(r, o);
                if (orr > r) r = orr;
            }
            int widx = 32767 - (int)((r >> 17) & 0x7FFFull);
            widx = __shfl(widx, 0);
            // winner coords from immutable input (L2-resident), lanes 0-2
            float cv = 0.0f;
            if (lane == 0)      cv = X[widx];
            else if (lane == 1) cv = Y[widx];
            else if (lane == 2) cv = Z[widx];
            // wave 0 gets coords via shfl (no LDS read-after-write hazard)
            const float nlx = __shfl(cv, 0);
            const float nly = __shfl(cv, 1);
            const float nlz = __shfl(cv, 2);
            // post to LDS for scan waves; release orders the ds_writes
            if (lane == 0)      swx = cv;
            else if (lane == 1) swy = cv;
            else if (lane == 2) swz = cv;
            if (lane == 0)
                __hip_atomic_store(&swtag, tag, __ATOMIC_RELEASE,
                                   __HIP_MEMORY_SCOPE_WORKGROUP);
            if (j == 0 && lane < 3)                      // output: AFTER release
                outb[(size_t)lane * FPS_M + s] = cv;
            lx = nlx;
            ly = nly;
            lz = nlz;
        }
    }
}

extern "C" void kernel_launch(void* const* d_in, const int* in_sizes, int n_in,
                              void* d_out, int out_size, void* d_ws, size_t ws_size,
                              hipStream_t stream) {
    const float* pts = (const float*)d_in[0];   // [16, 3, 32768] fp32
    float* out = (float*)d_out;                 // [16, 3, 2048] fp32
    ull* ws = (ull*)d_ws;                       // 16 batches x 16 words = 2 KB
    void* args[] = { (void*)&pts, (void*)&out, (void*)&ws };
    hipLaunchCooperativeKernel((const void*)fps_kernel,
                               dim3(FPS_B * BLK_PER_B), dim3(FPS_T),
                               args, 0, stream);
}

// Round 13
// 2239.895 us; speedup vs baseline: 2.3731x; 2.3731x over previous
//
#include <hip/hip_runtime.h>

#define FPS_N 32768
#define FPS_M 2048
#define FPS_B 16
#define BLK_PER_B 8
#define FPS_T 512
#define PTS (FPS_N / BLK_PER_B)   // 4096 points per block
#define PPT (PTS / FPS_T)         // 8 points per thread
#define NWAVE (FPS_T / 64)        // 8 waves
#define KPUB 7                    // candidates published per block
#define RING 56                   // max selections per epoch (= pool size)

typedef unsigned long long ull;

// butterfly u64 max: result in ALL lanes
__device__ __forceinline__ ull bfly_max_u64(ull v) {
#pragma unroll
    for (int o = 32; o > 0; o >>= 1) {
        ull ov = __shfl_xor(v, o, 64);
        if (ov > v) v = ov;
    }
    return v;
}

// EXACT LAZY-BATCHED FPS. 8 blocks/batch, cooperative. Rounds 9-12 showed
// ~5k cyc/selection is the floor for one-consensus-per-selection; this
// kernel amortizes the consensus over t selections per epoch:
//  A. apply pending ring of selected points to dist[] (min-chain: bitwise
//     identical to the reference's sequential updates).
//  B. per-wave top-9 by packed value (masked argmax, pk in regs).
//  C. wave 0: top-8 of the 72-word union => block top-7 (publish) and
//     vcut_block = max(8th-of-union, max per-wave 9th) >= every unpublished
//     point of this block.
//  D/E. publish 7 candidates + vcut (tagged, relaxed agent); poll all 64.
//  F-H. SIM (redundant on every block, deterministic): pool = 56 candidates
//     with coords from the immutable input; repeatedly take pool u64-max W;
//     while W > vcut_global it is EXACTLY the global argmax (non-pool values
//     only decrease and are <= vcut); update pool members vs the selection
//     with the same IEEE ops the batched pass will apply. Ring + count stay
//     lockstep-identical across blocks.
// packed = dist_bits<<32 | (32767-gidx)<<17  (u64 order == np.argmax
// first-occurrence; dist>=0 so IEEE bits are monotone). tag = epoch (<=2047,
// 12 bits; ws 0xAA poison field 0xAAA=2730 never matches). Parity
// double-buffered slots (reuse at e+2 provably post-consumption).
// >=1 selection/epoch guaranteed (global max is in the pool, > vcut).
// Coords in 24 VGPRs (A/B run LDS-free); waves_per_eu(2,2) pins the
// allocator grant at 128 (round-4 evidence) -- demand ~95, no spill.
// Numerics: contract off, (dx*dx+dy*dy)+dz*dz, min via ?:, no fma.
__global__ __launch_bounds__(FPS_T)
__attribute__((amdgpu_flat_work_group_size(FPS_T, FPS_T)))
__attribute__((amdgpu_waves_per_eu(2, 2)))
void fps_kernel(const float* __restrict__ pts, float* __restrict__ out,
                ull* __restrict__ ws) {
#pragma clang fp contract(off)
    __shared__ ull wtop[NWAVE * 9];     // 72 per-wave top-9 words
    __shared__ float srx[RING], sry[RING], srz[RING];
    __shared__ int sst;

    const int blk = blockIdx.x;
    const int b = blk & 15;             // batch
    const int j = blk >> 4;             // block-within-batch 0..7
    const int tid = threadIdx.x;
    const int wv = tid >> 6;
    const int lane = tid & 63;
    const float* __restrict__ X = pts + (size_t)b * 3 * FPS_N;
    const float* __restrict__ Y = X + FPS_N;
    const float* __restrict__ Z = Y + FPS_N;
    const int off = j * PTS;
    float* __restrict__ outb = out + (size_t)b * 3 * FPS_M;
    ull* __restrict__ wsb = ws + (size_t)b * 128;  // 2 par x 64 words

    // coords in registers; coalesced loads (stride FPS_T per k)
    float cx[PPT], cy[PPT], cz[PPT], dist[PPT];
#pragma unroll
    for (int k = 0; k < PPT; ++k) {
        const int q = k * FPS_T + tid;
        cx[k] = X[off + q];
        cy[k] = Y[off + q];
        cz[k] = Z[off + q];
        dist[k] = 1e10f;
    }
    if (tid == 0) {                     // initial ring = {point 0}
        srx[0] = X[0]; sry[0] = Y[0]; srz[0] = Z[0];
        sst = 1;
        if (j == 0) {                   // emit selection 0
            outb[0] = X[0]; outb[FPS_M] = Y[0]; outb[2 * FPS_M] = Z[0];
        }
    }
    __syncthreads();

    int count = 1;                      // selections emitted (incl. p0)
    int st = 1;                         // pending ring size
    int e = 0;                          // epoch counter == exchange tag

    while (count < FPS_M) {
        ++e;
        // ---- A: apply pending ring (bitwise == sequential reference) ----
        for (int u = 0; u < st; ++u) {
            const float wx = srx[u], wy = sry[u], wz = srz[u];
#pragma unroll
            for (int k = 0; k < PPT; ++k) {
                float dx = cx[k] - wx, dy = cy[k] - wy, dz = cz[k] - wz;
                float d = (dx * dx + dy * dy) + dz * dz;
                dist[k] = d < dist[k] ? d : dist[k];
            }
        }
        // ---- B: per-wave top-9 (masked argmax over packed regs) ----
        ull pk[PPT];
#pragma unroll
        for (int k = 0; k < PPT; ++k) {
            const unsigned g = (unsigned)(off + k * FPS_T + tid);
            pk[k] = ((ull)__float_as_uint(dist[k]) << 32)
                  | ((ull)(32767u - g) << 17);
        }
        for (int it = 0; it < 9; ++it) {
            ull m = pk[0];
#pragma unroll
            for (int k = 1; k < PPT; ++k)
                if (pk[k] > m) m = pk[k];
            ull W = bfly_max_u64(m);
            if (lane == 0) wtop[wv * 9 + it] = W;
#pragma unroll
            for (int k = 0; k < PPT; ++k)
                if (pk[k] == W) pk[k] = 0;      // unique -> exact masking
        }
        __syncthreads();

        if (wv == 0) {
            // ---- C: block top-8 of 72 + vcut ----
            ull av = wtop[lane];
            ull bv = (lane < 8) ? wtop[64 + lane] : 0;
            ull myc = 0, e8 = 0;
            for (int it = 0; it < 8; ++it) {
                ull m = av > bv ? av : bv;
                ull W = bfly_max_u64(m);
                if (it == lane) myc = W;        // lanes 0..6 = publishables
                if (it == 7) e8 = W;            // 8th best (all lanes)
                if (av == W) av = 0;
                if (bv == W) bv = 0;
            }
            ull wn = (lane < 8) ? wtop[lane * 9 + 8] : 0;  // per-wave 9ths
            ull w9m = bfly_max_u64(wn);
            ull vcut = e8 > w9m ? e8 : w9m;
            const ull tag = (ull)(unsigned)e;
            ull* base = wsb + (e & 1) * 64;     // parity slot group
            // ---- D: publish 7 candidates + vcut ----
            if (lane < 8) {
                ull word = (lane < KPUB ? myc : vcut) | tag;
                __hip_atomic_store(base + j * 8 + lane, word,
                                   __ATOMIC_RELAXED, __HIP_MEMORY_SCOPE_AGENT);
            }
            // ---- E: poll all 64 words (8 blocks x 8) ----
            const int pj = lane >> 3, pw = lane & 7;
            ull* pa = base + pj * 8 + pw;
            ull val = 0;
            bool ok = false;
            for (int itp = 0; itp < (1 << 25); ++itp) {
                if (!ok) {
                    val = __hip_atomic_load(pa, __ATOMIC_RELAXED,
                                            __HIP_MEMORY_SCOPE_AGENT);
                    ok = ((unsigned)(val & 0xFFFull) == (unsigned)e);
                }
                if (__all(ok)) break;
            }
            // ---- F: global vcut ----
            ull vcutg = bfly_max_u64((pw == 7) ? val : 0);
            // ---- G: candidate coords from immutable input (L2 gather) ----
            ull cval = (pw < KPUB) ? val : 0;
            float ccx = 0.0f, ccy = 0.0f, ccz = 0.0f;
            if (cval) {
                const int gi = 32767 - (int)((cval >> 17) & 0x7FFFull);
                ccx = X[gi]; ccy = Y[gi]; ccz = Z[gi];
            }
            // ---- H: sim — exact selections while pool max > vcut ----
            int t = 0;
            while (t < RING && (count + t) < FPS_M) {
                ull W = bfly_max_u64(cval);
                if (W <= vcutg) break;          // hidden point might win: stop
                ull msk = __ballot(cval == W);  // unique -> one bit
                int wl = __ffsll((long long)msk) - 1;
                float wx = __shfl(ccx, wl, 64);
                float wy = __shfl(ccy, wl, 64);
                float wz = __shfl(ccz, wl, 64);
                if (lane == 0) { srx[t] = wx; sry[t] = wy; srz[t] = wz; }
                if (lane == wl) cval = 0;       // consume winner
                if (cval) {                     // update pool (same IEEE ops)
                    float dx = ccx - wx, dy = ccy - wy, dz = ccz - wz;
                    float d = (dx * dx + dy * dy) + dz * dz;
                    float df = __uint_as_float((unsigned)(cval >> 32));
                    float nd = d < df ? d : df;
                    cval = ((ull)__float_as_uint(nd) << 32)
                         | (cval & 0xFFFFFFFFull);
                }
                ++t;
            }
            if (lane == 0) sst = t;
        }
        __syncthreads();
        st = sst;
        if (j == 0) {                           // emit this epoch's selections
            for (int r = tid; r < st; r += FPS_T) {
                outb[count + r]             = srx[r];
                outb[FPS_M + count + r]     = sry[r];
                outb[2 * FPS_M + count + r] = srz[r];
            }
        }
        count += st;
    }
}

extern "C" void kernel_launch(void* const* d_in, const int* in_sizes, int n_in,
                              void* d_out, int out_size, void* d_ws, size_t ws_size,
                              hipStream_t stream) {
    const float* pts = (const float*)d_in[0];   // [16, 3, 32768] fp32
    float* out = (float*)d_out;                 // [16, 3, 2048] fp32
    ull* ws = (ull*)d_ws;                       // 16 x 128 words = 16 KB used
    void* args[] = { (void*)&pts, (void*)&out, (void*)&ws };
    hipLaunchCooperativeKernel((const void*)fps_kernel,
                               dim3(FPS_B * BLK_PER_B), dim3(FPS_T),
                               args, 0, stream);
}

// Round 14
// 1687.103 us; speedup vs baseline: 3.1506x; 1.3277x over previous
//
#include <hip/hip_runtime.h>

#define FPS_N 32768
#define FPS_M 2048
#define FPS_B 16
#define BLK_PER_B 8
#define FPS_T 576                 // 9 waves: wave 0 = comm, waves 1-8 = scan
#define SCT 512                   // scan threads
#define PTS (FPS_N / BLK_PER_B)   // 4096 points per block
#define PPT (PTS / SCT)           // 8 points per scan thread
#define RING 128

typedef unsigned long long ull;

// butterfly u64 max: result in ALL lanes
__device__ __forceinline__ ull bfly_max_u64(ull v) {
#pragma unroll
    for (int o = 32; o > 0; o >>= 1) {
        ull ov = __shfl_xor(v, o, 64);
        if (ov > v) v = ov;
    }
    return v;
}

// EXACT LAZY-BATCHED FPS v2. 8 blocks/batch, cooperative. vs round 13
// (2.24 ms): (1) WEAKER CUT -> BIGGER EPOCHS: each WAVE publishes its own
// top-2 + 3rd-best-as-cut straight to the LLC (no block funnel, no C phase,
// B = 3 extraction rounds not 9). vcut_global = max of 64 per-wave 3rds
// ~ global 25-30th best (r^3/24576 ~ 1 at r~29) vs r13's ~8th -> t grows
// ~3x, epochs shrink ~3x. Exactness: any published set S works as long as
// the cut >= every unpublished point (point not in S <= its wave's 3rd);
// values only decrease after epoch start; packed u64 = dist<<32|invidx<<17
// keeps np.argmax first-occurrence order. (2) PIPELINED APPLY: dedicated
// comm wave (wave 0) polls 192 words (3/lane), computes vcutg, fetches the
// 128 candidate coords (2/lane, L2), sims, and posts selections to an LDS
// ring with monotone release tags; scan waves apply entries AS POSTED
// (160 cyc/entry << sim's ~600) -> apply overlaps sim; then B + publish.
// Zero barriers in steady state.
// Parity-group reuse (e at e+2) safe: publish of e transitively requires
// every comm finished reading e-2. Ring slot reuse (i at i+128) safe: comm
// posts epoch e+1 only after all waves published e+1, which requires they
// fully applied e. Tags: epoch e <= 2047 (12 bits; ws 0xAA poison field
// 0xAAA=2730 never matches); ring tags = row number, monotone.
// Numerics bit-exact: contract off, (dx*dx+dy*dy)+dz*dz, min via ?:, no fma.
__global__ __launch_bounds__(FPS_T)
__attribute__((amdgpu_waves_per_eu(1)))
void fps_kernel(const float* __restrict__ pts, float* __restrict__ out,
                ull* __restrict__ ws) {
#pragma clang fp contract(off)
    __shared__ float srx[RING], sry[RING], srz[RING];
    __shared__ unsigned rtag[RING];
    __shared__ unsigned etot;           // (epoch<<16) | last_posted_row

    const int blk = blockIdx.x;
    const int b = blk & 15;             // batch
    const int j = blk >> 4;             // block-within-batch 0..7
    const int tid = threadIdx.x;
    const int lane = tid & 63;
    const float* __restrict__ X = pts + (size_t)b * 3 * FPS_N;
    const float* __restrict__ Y = X + FPS_N;
    const float* __restrict__ Z = Y + FPS_N;
    const int off = j * PTS;
    float* __restrict__ outb = out + (size_t)b * 3 * FPS_M;
    ull* __restrict__ wsb = ws + (size_t)b * 512;  // 2 parities x 256 words

    for (int q = tid; q < RING; q += FPS_T) rtag[q] = 0;
    if (tid == 0) etot = 0;
    __syncthreads();                    // only barrier (pre-loop)

    const float p0x = X[0], p0y = Y[0], p0z = Z[0];

    if (tid < 64) {
        // ================= comm wave =================
        if (j == 0 && lane == 0) {      // row 0 = point 0
            outb[0] = p0x; outb[FPS_M] = p0y; outb[2 * FPS_M] = p0z;
        }
        int last = 0;                   // last posted output row
        for (unsigned e = 1; last < FPS_M - 1; ++e) {
            ull* grp = wsb + (e & 1) * 256;
            // poll 192 words: candidates [0..127], cuts [128..191]
            ull* a0 = grp + lane;
            ull* a1 = grp + 64 + lane;
            ull* a2 = grp + 128 + lane;
            ull v0 = 0, v1 = 0, v2 = 0;
            bool k0 = false, k1 = false, k2 = false;
            for (int it = 0; it < (1 << 25); ++it) {
                if (!k0) { v0 = __hip_atomic_load(a0, __ATOMIC_RELAXED,
                               __HIP_MEMORY_SCOPE_AGENT);
                           k0 = ((unsigned)(v0 & 0xFFFull) == e); }
                if (!k1) { v1 = __hip_atomic_load(a1, __ATOMIC_RELAXED,
                               __HIP_MEMORY_SCOPE_AGENT);
                           k1 = ((unsigned)(v1 & 0xFFFull) == e); }
                if (!k2) { v2 = __hip_atomic_load(a2, __ATOMIC_RELAXED,
                               __HIP_MEMORY_SCOPE_AGENT);
                           k2 = ((unsigned)(v2 & 0xFFFull) == e); }
                if (__all(k0 && k1 && k2)) break;
            }
            const ull vcutg = bfly_max_u64(v2);   // max of 64 wave-3rds
            // candidate coords from immutable input (L2-resident)
            const int g0 = 32767 - (int)((v0 >> 17) & 0x7FFFull);
            const int g1 = 32767 - (int)((v1 >> 17) & 0x7FFFull);
            const float c0x = X[g0], c0y = Y[g0], c0z = Z[g0];
            const float c1x = X[g1], c1y = Y[g1], c1z = Z[g1];
            ull cv0 = v0, cv1 = v1;
            int posted = 0;
            // sim: exact while pool max beats the cut
            while (last < FPS_M - 1 && posted < RING) {
                ull m = cv0 > cv1 ? cv0 : cv1;
                ull W = bfly_max_u64(m);
                if (W <= vcutg) break;
                const bool own0 = (cv0 == W), own1 = (cv1 == W);
                float sx = own0 ? c0x : c1x;
                float sy = own0 ? c0y : c1y;
                float sz = own0 ? c0z : c1z;
                ull mk = __ballot(own0 || own1);   // unique word -> one bit
                int wl = __ffsll((long long)mk) - 1;
                const float wx = __shfl(sx, wl);
                const float wy = __shfl(sy, wl);
                const float wz = __shfl(sz, wl);
                if (own0) cv0 = 0;                 // consume winner
                if (own1) cv1 = 0;
                if (cv0) {                         // update pool, same IEEE ops
                    float dx = c0x - wx, dy = c0y - wy, dz = c0z - wz;
                    float d = (dx * dx + dy * dy) + dz * dz;
                    float df = __uint_as_float((unsigned)(cv0 >> 32));
                    float nd = d < df ? d : df;
                    cv0 = ((ull)__float_as_uint(nd) << 32) | (cv0 & 0xFFFFFFFFull);
                }
                if (cv1) {
                    float dx = c1x - wx, dy = c1y - wy, dz = c1z - wz;
                    float d = (dx * dx + dy * dy) + dz * dz;
                    float df = __uint_as_float((unsigned)(cv1 >> 32));
                    float nd = d < df ? d : df;
                    cv1 = ((ull)__float_as_uint(nd) << 32) | (cv1 & 0xFFFFFFFFull);
                }
                ++last; ++posted;
                const int slot = last & (RING - 1);
                if (lane == 0) {                   // post to ring, release tag
                    srx[slot] = wx; sry[slot] = wy; srz[slot] = wz;
                    __hip_atomic_store(&rtag[slot], (unsigned)last,
                                       __ATOMIC_RELEASE, __HIP_MEMORY_SCOPE_WORKGROUP);
                }
            }
            if (lane == 0)
                __hip_atomic_store(&etot, (e << 16) | (unsigned)last,
                                   __ATOMIC_RELAXED, __HIP_MEMORY_SCOPE_WORKGROUP);
        }
    } else {
        // ================= scan waves =================
        const int st = tid - 64;        // 0..511
        const int w = (tid >> 6) - 1;   // scan wave 0..7
        float cx[PPT], cy[PPT], cz[PPT], dist[PPT];
        unsigned inv[PPT];
#pragma unroll
        for (int k = 0; k < PPT; ++k) { // coords in regs; apply p0 inline
            const int g = off + k * SCT + st;
            cx[k] = X[g]; cy[k] = Y[g]; cz[k] = Z[g];
            float dx = cx[k] - p0x, dy = cy[k] - p0y, dz = cz[k] - p0z;
            dist[k] = (dx * dx + dy * dy) + dz * dz;
            inv[k] = 32767u - (unsigned)g;
        }
        unsigned applied = 0;           // rows applied beyond row 0
        for (unsigned e = 1;; ++e) {
            // B: wave top-3 (3 masked extraction rounds)
            ull pk[PPT];
#pragma unroll
            for (int k = 0; k < PPT; ++k)
                pk[k] = ((ull)__float_as_uint(dist[k]) << 32) | ((ull)inv[k] << 17);
            ull W1 = 0, W2 = 0, W3 = 0;
            for (int r = 0; r < 3; ++r) {
                ull m = pk[0];
#pragma unroll
                for (int k = 1; k < PPT; ++k)
                    if (pk[k] > m) m = pk[k];
                ull W = bfly_max_u64(m);
#pragma unroll
                for (int k = 0; k < PPT; ++k)
                    if (pk[k] == W) pk[k] = 0;     // unique -> exact mask
                if (r == 0) W1 = W; else if (r == 1) W2 = W; else W3 = W;
            }
            // publish: candidates at j*16+w*2+{0,1}, cut at 128+j*8+w
            ull* grp = wsb + (e & 1) * 256;
            if (lane == 0)
                __hip_atomic_store(grp + j * 16 + w * 2, W1 | (ull)e,
                                   __ATOMIC_RELAXED, __HIP_MEMORY_SCOPE_AGENT);
            else if (lane == 1)
                __hip_atomic_store(grp + j * 16 + w * 2 + 1, W2 | (ull)e,
                                   __ATOMIC_RELAXED, __HIP_MEMORY_SCOPE_AGENT);
            else if (lane == 2)
                __hip_atomic_store(grp + 128 + j * 8 + w, W3 | (ull)e,
                                   __ATOMIC_RELAXED, __HIP_MEMORY_SCOPE_AGENT);
            // apply phase: consume ring entries as they are posted
            unsigned last_row = 0;
            bool have = false;
            for (;;) {
                if (!have) {
                    unsigned u = __hip_atomic_load(&etot, __ATOMIC_RELAXED,
                                                   __HIP_MEMORY_SCOPE_WORKGROUP);
                    if ((u >> 16) == e) { last_row = u & 0xFFFFu; have = true; }
                }
                const unsigned want = applied + 1;
                if (!have || want <= last_row) {
                    const int slot = (int)(want & (RING - 1));
                    if (__hip_atomic_load(&rtag[slot], __ATOMIC_ACQUIRE,
                                          __HIP_MEMORY_SCOPE_WORKGROUP) == want) {
                        const float wx = srx[slot], wy = sry[slot], wz = srz[slot];
#pragma unroll
                        for (int k = 0; k < PPT; ++k) {
                            float dx = cx[k] - wx, dy = cy[k] - wy, dz = cz[k] - wz;
                            float d = (dx * dx + dy * dy) + dz * dz;
                            dist[k] = d < dist[k] ? d : dist[k];
                        }
                        if (j == 0 && w == 0 && lane < 3) {   // emit row
                            float cv = lane == 0 ? wx : (lane == 1 ? wy : wz);
                            outb[(size_t)lane * FPS_M + want] = cv;
                        }
                        applied = want;
                    }
                }
                if (have && applied == last_row) break;
            }
            if (last_row >= FPS_M - 1) break;
        }
    }
}

extern "C" void kernel_launch(void* const* d_in, const int* in_sizes, int n_in,
                              void* d_out, int out_size, void* d_ws, size_t ws_size,
                              hipStream_t stream) {
    const float* pts = (const float*)d_in[0];   // [16, 3, 32768] fp32
    float* out = (float*)d_out;                 // [16, 3, 2048] fp32
    ull* ws = (ull*)d_ws;                       // 16 x 512 words = 64 KB used
    void* args[] = { (void*)&pts, (void*)&out, (void*)&ws };
    hipLaunchCooperativeKernel((const void*)fps_kernel,
                               dim3(FPS_B * BLK_PER_B), dim3(FPS_T),
                               args, 0, stream);
}

// Round 15
// 1591.407 us; speedup vs baseline: 3.3401x; 1.0601x over previous
//
#include <hip/hip_runtime.h>

#define FPS_N 32768
#define FPS_M 2048
#define FPS_B 16
#define BLK_PER_B 8
#define FPS_T 576                 // 9 waves: wave 0 = comm, waves 1-8 = scan
#define SCT 512                   // scan threads
#define PTS (FPS_N / BLK_PER_B)   // 4096 points per block
#define PPT (PTS / SCT)           // 8 points per scan thread
#define KPUB 4                    // candidates published per wave
#define RING 128
#define WSTRIDE 640               // ws words per batch: 2 parities x 320

typedef unsigned long long ull;

// u64 max step via DPP (VALU pipe). old = self -> masked/invalid lanes
// return self (identity-safe). Verified correct in round 11 (passed).
#define DPP_MAX_STEP(ctrl, rmask)                                              \
    {                                                                          \
        unsigned plo = (unsigned)__builtin_amdgcn_update_dpp(                  \
            (int)lo, (int)lo, (ctrl), (rmask), 0xf, false);                    \
        unsigned phi = (unsigned)__builtin_amdgcn_update_dpp(                  \
            (int)hi, (int)hi, (ctrl), (rmask), 0xf, false);                    \
        if (phi > hi || (phi == hi && plo > lo)) { hi = phi; lo = plo; }       \
    }

// wave max valid in lane 63, then broadcast via readlane (scalar, ~free)
__device__ __forceinline__ ull wave_max_u64(ull v) {
    unsigned lo = (unsigned)v, hi = (unsigned)(v >> 32);
    DPP_MAX_STEP(0x111, 0xf)      // row_shr:1
    DPP_MAX_STEP(0x112, 0xf)      // row_shr:2
    DPP_MAX_STEP(0x114, 0xf)      // row_shr:4
    DPP_MAX_STEP(0x118, 0xf)      // row_shr:8  -> lane 15/31/47/63 row max
    DPP_MAX_STEP(0x142, 0xa)      // row_bcast:15 -> lanes 31/63
    DPP_MAX_STEP(0x143, 0xc)      // row_bcast:31 -> lane 63
    unsigned blo = (unsigned)__builtin_amdgcn_readlane((int)lo, 63);
    unsigned bhi = (unsigned)__builtin_amdgcn_readlane((int)hi, 63);
    return ((ull)bhi << 32) | blo;
}

__device__ __forceinline__ float readlane_f(float v, int l) {
    return __uint_as_float(
        (unsigned)__builtin_amdgcn_readlane((int)__float_as_uint(v), l));
}

// EXACT LAZY-BATCHED FPS v3. 8 blocks/batch, cooperative, wave-specialized.
// vs round 14 (1.69 ms; back-solved t~3.4, ~600 epochs):
//  (1) DEEPER CUT: each wave publishes top-4 + 5th-best-as-cut (pool 256).
//      vcutg = max of 64 wave-5ths ~ global 50-60th initial rank -> t ~2x,
//      epochs ~2x down. Exactness: unpublished point <= its wave's 5th <=
//      vcutg; values only decrease after epoch start; packed u64
//      (dist<<32 | invidx<<17 | tag) preserves np.argmax first-occurrence.
//  (2) DPP max + readlane broadcast on all hot reduces (sim loop, B
//      extraction, vcut): ~80 cyc vs ~240 for 6-level shfl_xor bfly; winner
//      coords broadcast via dynamic-lane readlane (3x10 cyc vs 3 shfls).
// Structure from r14: comm wave polls 5 words/lane, sims, posts selections
// to an LDS ring (release tags = row number, monotone); scan waves apply
// ring entries as posted (overlaps sim), then B + publish. Zero steady-state
// barriers. Parity-group reuse at e+2 and ring-slot reuse at +128 are both
// provably post-consumption (publish of e requires full apply of e-1).
// Tags: epoch e <= 2047 (12 bits; ws 0xAA poison field 0xAAA=2730 never
// matches). Numerics bit-exact: contract off, (dx*dx+dy*dy)+dz*dz, no fma.
__global__ __launch_bounds__(FPS_T)
__attribute__((amdgpu_waves_per_eu(1)))
void fps_kernel(const float* __restrict__ pts, float* __restrict__ out,
                ull* __restrict__ ws) {
#pragma clang fp contract(off)
    __shared__ float srx[RING], sry[RING], srz[RING];
    __shared__ unsigned rtag[RING];
    __shared__ unsigned etot;           // (epoch<<16) | last_posted_row

    const int blk = blockIdx.x;
    const int b = blk & 15;             // batch
    const int j = blk >> 4;             // block-within-batch 0..7
    const int tid = threadIdx.x;
    const int lane = tid & 63;
    const float* __restrict__ X = pts + (size_t)b * 3 * FPS_N;
    const float* __restrict__ Y = X + FPS_N;
    const float* __restrict__ Z = Y + FPS_N;
    const int off = j * PTS;
    float* __restrict__ outb = out + (size_t)b * 3 * FPS_M;
    ull* __restrict__ wsb = ws + (size_t)b * WSTRIDE;

    for (int q = tid; q < RING; q += FPS_T) rtag[q] = 0;
    if (tid == 0) etot = 0;
    __syncthreads();                    // only barrier (pre-loop)

    const float p0x = X[0], p0y = Y[0], p0z = Z[0];

    if (tid < 64) {
        // ================= comm wave =================
        if (j == 0 && lane == 0) {      // row 0 = point 0
            outb[0] = p0x; outb[FPS_M] = p0y; outb[2 * FPS_M] = p0z;
        }
        int last = 0;
        for (unsigned e = 1; last < FPS_M - 1; ++e) {
            ull* grp = wsb + (e & 1) * 320;
            // poll: lane l owns wave l -> 4 cand words (contig) + 1 cut word
            ull* ca = grp + lane * 4;
            ull* cu = grp + 256 + lane;
            ull c0 = 0, c1 = 0, c2 = 0, c3 = 0, cw = 0;
            bool k0 = false, k1 = false, k2 = false, k3 = false, k4 = false;
            for (int it = 0; it < (1 << 25); ++it) {
                if (!k0) { c0 = __hip_atomic_load(ca + 0, __ATOMIC_RELAXED,
                               __HIP_MEMORY_SCOPE_AGENT);
                           k0 = ((unsigned)(c0 & 0xFFFull) == e); }
                if (!k1) { c1 = __hip_atomic_load(ca + 1, __ATOMIC_RELAXED,
                               __HIP_MEMORY_SCOPE_AGENT);
                           k1 = ((unsigned)(c1 & 0xFFFull) == e); }
                if (!k2) { c2 = __hip_atomic_load(ca + 2, __ATOMIC_RELAXED,
                               __HIP_MEMORY_SCOPE_AGENT);
                           k2 = ((unsigned)(c2 & 0xFFFull) == e); }
                if (!k3) { c3 = __hip_atomic_load(ca + 3, __ATOMIC_RELAXED,
                               __HIP_MEMORY_SCOPE_AGENT);
                           k3 = ((unsigned)(c3 & 0xFFFull) == e); }
                if (!k4) { cw = __hip_atomic_load(cu, __ATOMIC_RELAXED,
                               __HIP_MEMORY_SCOPE_AGENT);
                           k4 = ((unsigned)(cw & 0xFFFull) == e); }
                if (__all(k0 && k1 && k2 && k3 && k4)) break;
            }
            const ull vcutg = wave_max_u64(cw);   // max of 64 wave-5ths
            // pool: 4 candidates/lane; coords from immutable input (L2)
            ull cv[KPUB] = {c0, c1, c2, c3};
            float ccx[KPUB], ccy[KPUB], ccz[KPUB];
#pragma unroll
            for (int c = 0; c < KPUB; ++c) {
                const int g = 32767 - (int)((cv[c] >> 17) & 0x7FFFull);
                ccx[c] = X[g]; ccy[c] = Y[g]; ccz[c] = Z[g];
            }
            int posted = 0;
            while (last < FPS_M - 1 && posted < RING) {
                ull m = cv[0];
#pragma unroll
                for (int c = 1; c < KPUB; ++c)
                    if (cv[c] > m) m = cv[c];
                const ull W = wave_max_u64(m);    // uniform in all lanes
                if (W <= vcutg) break;
                // winner lane + in-lane coord select (words globally unique)
                bool own = false;
                float sx = 0.0f, sy = 0.0f, sz = 0.0f;
#pragma unroll
                for (int c = 0; c < KPUB; ++c) {
                    const bool h = (cv[c] == W);
                    own |= h;
                    sx = h ? ccx[c] : sx;
                    sy = h ? ccy[c] : sy;
                    sz = h ? ccz[c] : sz;
                    cv[c] = h ? 0 : cv[c];        // consume
                }
                const ull mk = __ballot(own);     // exactly one bit
                const int wl = __ffsll((long long)mk) - 1;
                const float wx = readlane_f(sx, wl);
                const float wy = readlane_f(sy, wl);
                const float wz = readlane_f(sz, wl);
                // update pool (same IEEE ops as the batched apply)
#pragma unroll
                for (int c = 0; c < KPUB; ++c) {
                    float dx = ccx[c] - wx, dy = ccy[c] - wy, dz = ccz[c] - wz;
                    float d = (dx * dx + dy * dy) + dz * dz;
                    float df = __uint_as_float((unsigned)(cv[c] >> 32));
                    float nd = d < df ? d : df;   // consumed (0) stays 0
                    cv[c] = ((ull)__float_as_uint(nd) << 32)
                          | (cv[c] & 0xFFFFFFFFull);
                }
                ++last; ++posted;
                const int slot = last & (RING - 1);
                if (lane == 0) {                  // post to ring, release tag
                    srx[slot] = wx; sry[slot] = wy; srz[slot] = wz;
                    __hip_atomic_store(&rtag[slot], (unsigned)last,
                                       __ATOMIC_RELEASE,
                                       __HIP_MEMORY_SCOPE_WORKGROUP);
                }
            }
            if (lane == 0)
                __hip_atomic_store(&etot, (e << 16) | (unsigned)last,
                                   __ATOMIC_RELAXED, __HIP_MEMORY_SCOPE_WORKGROUP);
        }
    } else {
        // ================= scan waves =================
        const int st = tid - 64;        // 0..511
        const int w = (tid >> 6) - 1;   // scan wave 0..7
        const int wid = j * 8 + w;      // wave id within batch 0..63
        float cx[PPT], cy[PPT], cz[PPT], dist[PPT];
        unsigned inv[PPT];
#pragma unroll
        for (int k = 0; k < PPT; ++k) { // coords in regs; apply p0 inline
            const int g = off + k * SCT + st;
            cx[k] = X[g]; cy[k] = Y[g]; cz[k] = Z[g];
            float dx = cx[k] - p0x, dy = cy[k] - p0y, dz = cz[k] - p0z;
            dist[k] = (dx * dx + dy * dy) + dz * dz;
            inv[k] = 32767u - (unsigned)g;
        }
        unsigned applied = 0;
        for (unsigned e = 1;; ++e) {
            // B: wave top-5 via 5 masked DPP extraction rounds
            ull pk[PPT];
#pragma unroll
            for (int k = 0; k < PPT; ++k)
                pk[k] = ((ull)__float_as_uint(dist[k]) << 32) | ((ull)inv[k] << 17);
            ull Wr[KPUB + 1];
#pragma unroll
            for (int r = 0; r < KPUB + 1; ++r) {
                ull m = pk[0];
#pragma unroll
                for (int k = 1; k < PPT; ++k)
                    if (pk[k] > m) m = pk[k];
                const ull W = wave_max_u64(m);
                Wr[r] = W;
#pragma unroll
                for (int k = 0; k < PPT; ++k)
                    if (pk[k] == W) pk[k] = 0;    // unique -> exact mask
            }
            // publish: lanes 0-3 candidates, lane 4 the cut
            ull* grp = wsb + (e & 1) * 320;
            if (lane < KPUB) {
                ull wv = Wr[0];
                wv = (lane == 1) ? Wr[1] : wv;
                wv = (lane == 2) ? Wr[2] : wv;
                wv = (lane == 3) ? Wr[3] : wv;
                __hip_atomic_store(grp + wid * 4 + lane, wv | (ull)e,
                                   __ATOMIC_RELAXED, __HIP_MEMORY_SCOPE_AGENT);
            } else if (lane == KPUB) {
                __hip_atomic_store(grp + 256 + wid, Wr[KPUB] | (ull)e,
                                   __ATOMIC_RELAXED, __HIP_MEMORY_SCOPE_AGENT);
            }
            // apply: consume ring entries as they are posted
            unsigned last_row = 0;
            bool have = false;
            for (;;) {
                if (!have) {
                    unsigned u = __hip_atomic_load(&etot, __ATOMIC_RELAXED,
                                                   __HIP_MEMORY_SCOPE_WORKGROUP);
                    if ((u >> 16) == e) { last_row = u & 0xFFFFu; have = true; }
                }
                const unsigned want = applied + 1;
                if (!have || want <= last_row) {
                    const int slot = (int)(want & (RING - 1));
                    if (__hip_atomic_load(&rtag[slot], __ATOMIC_ACQUIRE,
                                          __HIP_MEMORY_SCOPE_WORKGROUP) == want) {
                        const float wx = srx[slot], wy = sry[slot], wz = srz[slot];
#pragma unroll
                        for (int k = 0; k < PPT; ++k) {
                            float dx = cx[k] - wx, dy = cy[k] - wy, dz = cz[k] - wz;
                            float d = (dx * dx + dy * dy) + dz * dz;
                            dist[k] = d < dist[k] ? d : dist[k];
                        }
                        if (j == 0 && w == 0 && lane < 3) {   // emit row
                            float cvv = lane == 0 ? wx : (lane == 1 ? wy : wz);
                            outb[(size_t)lane * FPS_M + want] = cvv;
                        }
                        applied = want;
                    }
                }
                if (have && applied == last_row) break;
            }
            if (last_row >= FPS_M - 1) break;
        }
    }
}

extern "C" void kernel_launch(void* const* d_in, const int* in_sizes, int n_in,
                              void* d_out, int out_size, void* d_ws, size_t ws_size,
                              hipStream_t stream) {
    const float* pts = (const float*)d_in[0];   // [16, 3, 32768] fp32
    float* out = (float*)d_out;                 // [16, 3, 2048] fp32
    ull* ws = (ull*)d_ws;                       // 16 x 640 words = 80 KB used
    void* args[] = { (void*)&pts, (void*)&out, (void*)&ws };
    hipLaunchCooperativeKernel((const void*)fps_kernel,
                               dim3(FPS_B * BLK_PER_B), dim3(FPS_T),
                               args, 0, stream);
}

// Round 16
// 1580.057 us; speedup vs baseline: 3.3641x; 1.0072x over previous
//
#include <hip/hip_runtime.h>

#define FPS_N 32768
#define FPS_M 2048
#define FPS_B 16
#define BLK_PER_B 8
#define FPS_T 576                 // 9 waves: wave 0 = comm, waves 1-8 = scan
#define SCT 512                   // scan threads
#define PTS (FPS_N / BLK_PER_B)   // 4096 points per block
#define PPT (PTS / SCT)           // 8 points per scan thread
#define KPUB 4                    // candidates published per wave
#define RING 128
#define WSTRIDE 640               // ws words per batch: 2 parities x 320

typedef unsigned long long ull;

// u64 max step via DPP (VALU pipe). old = self -> masked/invalid lanes
// return self (identity-safe). Verified correct rounds 11/15.
#define DPP_MAX_STEP(ctrl, rmask)                                              \
    {                                                                          \
        unsigned plo = (unsigned)__builtin_amdgcn_update_dpp(                  \
            (int)lo, (int)lo, (ctrl), (rmask), 0xf, false);                    \
        unsigned phi = (unsigned)__builtin_amdgcn_update_dpp(                  \
            (int)hi, (int)hi, (ctrl), (rmask), 0xf, false);                    \
        if (phi > hi || (phi == hi && plo > lo)) { hi = phi; lo = plo; }       \
    }

// wave max valid in lane 63, broadcast via readlane
__device__ __forceinline__ ull wave_max_u64(ull v) {
    unsigned lo = (unsigned)v, hi = (unsigned)(v >> 32);
    DPP_MAX_STEP(0x111, 0xf)      // row_shr:1
    DPP_MAX_STEP(0x112, 0xf)      // row_shr:2
    DPP_MAX_STEP(0x114, 0xf)      // row_shr:4
    DPP_MAX_STEP(0x118, 0xf)      // row_shr:8
    DPP_MAX_STEP(0x142, 0xa)      // row_bcast:15
    DPP_MAX_STEP(0x143, 0xc)      // row_bcast:31 -> lane 63
    unsigned blo = (unsigned)__builtin_amdgcn_readlane((int)lo, 63);
    unsigned bhi = (unsigned)__builtin_amdgcn_readlane((int)hi, 63);
    return ((ull)bhi << 32) | blo;
}

__device__ __forceinline__ float readlane_f(float v, int l) {
    return __uint_as_float(
        (unsigned)__builtin_amdgcn_readlane((int)__float_as_uint(v), l));
}

// EXACT LAZY-BATCHED FPS v4. Identical structure to round 15 (1.59 ms) with
// ONE change: s_sleep(1) on the MISS PATH of every spin loop.
// Round-15 diagnosis: chain work sums to ~3.5k cyc/epoch but measured is
// ~8.2k. The block runs 9 waves on 4 SIMDs (one SIMD hosts 3). Spin loops
// (comm LLC poll, 8 scan waves on rtag/etot) issue at full rate while
// spinning -> during every serial phase the co-resident spinners steal ~2/3
// of the working wave's issue slots (VALUBusy 20% >> real work). A sleeping
// wave issues nothing. Sleep only AFTER a failed check (round-10 lesson:
// never sleep on the path before the first check); adds <=~32 cyc average
// handoff latency, reclaims the 2-3x issue dilation.
// Everything else unchanged from r15: per-wave top-4 + 5th-as-cut published
// straight to LLC (packed u64 = dist<<32|invidx<<17|tag; u64 order ==
// np.argmax first-occurrence), comm wave polls 5 words/lane, sims while
// pool max > vcutg, posts selections to LDS ring (release tags, monotone);
// scan waves apply as posted, then B (5 masked DPP extractions) + publish.
// Zero steady-state barriers. Parity reuse at e+2 / ring reuse at +128
// provably post-consumption. Tags <= 2047 (12 bits; 0xAA poison field
// 0xAAA=2730 never matches). Numerics bit-exact: contract off,
// (dx*dx+dy*dy)+dz*dz, min via ?:, no fma.
__global__ __launch_bounds__(FPS_T)
__attribute__((amdgpu_waves_per_eu(1)))
void fps_kernel(const float* __restrict__ pts, float* __restrict__ out,
                ull* __restrict__ ws) {
#pragma clang fp contract(off)
    __shared__ float srx[RING], sry[RING], srz[RING];
    __shared__ unsigned rtag[RING];
    __shared__ unsigned etot;           // (epoch<<16) | last_posted_row

    const int blk = blockIdx.x;
    const int b = blk & 15;             // batch
    const int j = blk >> 4;             // block-within-batch 0..7
    const int tid = threadIdx.x;
    const int lane = tid & 63;
    const float* __restrict__ X = pts + (size_t)b * 3 * FPS_N;
    const float* __restrict__ Y = X + FPS_N;
    const float* __restrict__ Z = Y + FPS_N;
    const int off = j * PTS;
    float* __restrict__ outb = out + (size_t)b * 3 * FPS_M;
    ull* __restrict__ wsb = ws + (size_t)b * WSTRIDE;

    for (int q = tid; q < RING; q += FPS_T) rtag[q] = 0;
    if (tid == 0) etot = 0;
    __syncthreads();                    // only barrier (pre-loop)

    const float p0x = X[0], p0y = Y[0], p0z = Z[0];

    if (tid < 64) {
        // ================= comm wave =================
        if (j == 0 && lane == 0) {      // row 0 = point 0
            outb[0] = p0x; outb[FPS_M] = p0y; outb[2 * FPS_M] = p0z;
        }
        int last = 0;
        for (unsigned e = 1; last < FPS_M - 1; ++e) {
            ull* grp = wsb + (e & 1) * 320;
            // poll: lane l owns wave l -> 4 cand words (contig) + 1 cut word
            ull* ca = grp + lane * 4;
            ull* cu = grp + 256 + lane;
            ull c0 = 0, c1 = 0, c2 = 0, c3 = 0, cw = 0;
            bool k0 = false, k1 = false, k2 = false, k3 = false, k4 = false;
            for (int it = 0; it < (1 << 25); ++it) {
                if (!k0) { c0 = __hip_atomic_load(ca + 0, __ATOMIC_RELAXED,
                               __HIP_MEMORY_SCOPE_AGENT);
                           k0 = ((unsigned)(c0 & 0xFFFull) == e); }
                if (!k1) { c1 = __hip_atomic_load(ca + 1, __ATOMIC_RELAXED,
                               __HIP_MEMORY_SCOPE_AGENT);
                           k1 = ((unsigned)(c1 & 0xFFFull) == e); }
                if (!k2) { c2 = __hip_atomic_load(ca + 2, __ATOMIC_RELAXED,
                               __HIP_MEMORY_SCOPE_AGENT);
                           k2 = ((unsigned)(c2 & 0xFFFull) == e); }
                if (!k3) { c3 = __hip_atomic_load(ca + 3, __ATOMIC_RELAXED,
                               __HIP_MEMORY_SCOPE_AGENT);
                           k3 = ((unsigned)(c3 & 0xFFFull) == e); }
                if (!k4) { cw = __hip_atomic_load(cu, __ATOMIC_RELAXED,
                               __HIP_MEMORY_SCOPE_AGENT);
                           k4 = ((unsigned)(cw & 0xFFFull) == e); }
                if (__all(k0 && k1 && k2 && k3 && k4)) break;
                __builtin_amdgcn_s_sleep(1);    // miss: free the SIMD
            }
            const ull vcutg = wave_max_u64(cw);   // max of 64 wave-5ths
            // pool: 4 candidates/lane; coords from immutable input (L2)
            ull cv[KPUB] = {c0, c1, c2, c3};
            float ccx[KPUB], ccy[KPUB], ccz[KPUB];
#pragma unroll
            for (int c = 0; c < KPUB; ++c) {
                const int g = 32767 - (int)((cv[c] >> 17) & 0x7FFFull);
                ccx[c] = X[g]; ccy[c] = Y[g]; ccz[c] = Z[g];
            }
            int posted = 0;
            while (last < FPS_M - 1 && posted < RING) {
                ull m = cv[0];
#pragma unroll
                for (int c = 1; c < KPUB; ++c)
                    if (cv[c] > m) m = cv[c];
                const ull W = wave_max_u64(m);    // uniform in all lanes
                if (W <= vcutg) break;
                // winner lane + in-lane coord select (words globally unique)
                bool own = false;
                float sx = 0.0f, sy = 0.0f, sz = 0.0f;
#pragma unroll
                for (int c = 0; c < KPUB; ++c) {
                    const bool h = (cv[c] == W);
                    own |= h;
                    sx = h ? ccx[c] : sx;
                    sy = h ? ccy[c] : sy;
                    sz = h ? ccz[c] : sz;
                    cv[c] = h ? 0 : cv[c];        // consume
                }
                const ull mk = __ballot(own);     // exactly one bit
                const int wl = __ffsll((long long)mk) - 1;
                const float wx = readlane_f(sx, wl);
                const float wy = readlane_f(sy, wl);
                const float wz = readlane_f(sz, wl);
                // update pool (same IEEE ops as the batched apply)
#pragma unroll
                for (int c = 0; c < KPUB; ++c) {
                    float dx = ccx[c] - wx, dy = ccy[c] - wy, dz = ccz[c] - wz;
                    float d = (dx * dx + dy * dy) + dz * dz;
                    float df = __uint_as_float((unsigned)(cv[c] >> 32));
                    float nd = d < df ? d : df;   // consumed (0) stays 0
                    cv[c] = ((ull)__float_as_uint(nd) << 32)
                          | (cv[c] & 0xFFFFFFFFull);
                }
                ++last; ++posted;
                const int slot = last & (RING - 1);
                if (lane == 0) {                  // post to ring, release tag
                    srx[slot] = wx; sry[slot] = wy; srz[slot] = wz;
                    __hip_atomic_store(&rtag[slot], (unsigned)last,
                                       __ATOMIC_RELEASE,
                                       __HIP_MEMORY_SCOPE_WORKGROUP);
                }
            }
            if (lane == 0)
                __hip_atomic_store(&etot, (e << 16) | (unsigned)last,
                                   __ATOMIC_RELAXED, __HIP_MEMORY_SCOPE_WORKGROUP);
        }
    } else {
        // ================= scan waves =================
        const int st = tid - 64;        // 0..511
        const int w = (tid >> 6) - 1;   // scan wave 0..7
        const int wid = j * 8 + w;      // wave id within batch 0..63
        float cx[PPT], cy[PPT], cz[PPT], dist[PPT];
        unsigned inv[PPT];
#pragma unroll
        for (int k = 0; k < PPT; ++k) { // coords in regs; apply p0 inline
            const int g = off + k * SCT + st;
            cx[k] = X[g]; cy[k] = Y[g]; cz[k] = Z[g];
            float dx = cx[k] - p0x, dy = cy[k] - p0y, dz = cz[k] - p0z;
            dist[k] = (dx * dx + dy * dy) + dz * dz;
            inv[k] = 32767u - (unsigned)g;
        }
        unsigned applied = 0;
        for (unsigned e = 1;; ++e) {
            // B: wave top-5 via 5 masked DPP extraction rounds
            ull pk[PPT];
#pragma unroll
            for (int k = 0; k < PPT; ++k)
                pk[k] = ((ull)__float_as_uint(dist[k]) << 32) | ((ull)inv[k] << 17);
            ull Wr[KPUB + 1];
#pragma unroll
            for (int r = 0; r < KPUB + 1; ++r) {
                ull m = pk[0];
#pragma unroll
                for (int k = 1; k < PPT; ++k)
                    if (pk[k] > m) m = pk[k];
                const ull W = wave_max_u64(m);
                Wr[r] = W;
#pragma unroll
                for (int k = 0; k < PPT; ++k)
                    if (pk[k] == W) pk[k] = 0;    // unique -> exact mask
            }
            // publish: lanes 0-3 candidates, lane 4 the cut
            ull* grp = wsb + (e & 1) * 320;
            if (lane < KPUB) {
                ull wv = Wr[0];
                wv = (lane == 1) ? Wr[1] : wv;
                wv = (lane == 2) ? Wr[2] : wv;
                wv = (lane == 3) ? Wr[3] : wv;
                __hip_atomic_store(grp + wid * 4 + lane, wv | (ull)e,
                                   __ATOMIC_RELAXED, __HIP_MEMORY_SCOPE_AGENT);
            } else if (lane == KPUB) {
                __hip_atomic_store(grp + 256 + wid, Wr[KPUB] | (ull)e,
                                   __ATOMIC_RELAXED, __HIP_MEMORY_SCOPE_AGENT);
            }
            // apply: consume ring entries as posted; sleep when idle
            unsigned last_row = 0;
            bool have = false;
            for (;;) {
                bool did = false;
                if (!have) {
                    unsigned u = __hip_atomic_load(&etot, __ATOMIC_RELAXED,
                                                   __HIP_MEMORY_SCOPE_WORKGROUP);
                    if ((u >> 16) == e) { last_row = u & 0xFFFFu; have = true; did = true; }
                }
                const unsigned want = applied + 1;
                if (!have || want <= last_row) {
                    const int slot = (int)(want & (RING - 1));
                    if (__hip_atomic_load(&rtag[slot], __ATOMIC_ACQUIRE,
                                          __HIP_MEMORY_SCOPE_WORKGROUP) == want) {
                        const float wx = srx[slot], wy = sry[slot], wz = srz[slot];
#pragma unroll
                        for (int k = 0; k < PPT; ++k) {
                            float dx = cx[k] - wx, dy = cy[k] - wy, dz = cz[k] - wz;
                            float d = (dx * dx + dy * dy) + dz * dz;
                            dist[k] = d < dist[k] ? d : dist[k];
                        }
                        if (j == 0 && w == 0 && lane < 3) {   // emit row
                            float cvv = lane == 0 ? wx : (lane == 1 ? wy : wz);
                            outb[(size_t)lane * FPS_M + want] = cvv;
                        }
                        applied = want;
                        did = true;
                    }
                }
                if (have && applied == last_row) break;
                if (!did) __builtin_amdgcn_s_sleep(1);  // idle: free the SIMD
            }
            if (last_row >= FPS_M - 1) break;
        }
    }
}

extern "C" void kernel_launch(void* const* d_in, const int* in_sizes, int n_in,
                              void* d_out, int out_size, void* d_ws, size_t ws_size,
                              hipStream_t stream) {
    const float* pts = (const float*)d_in[0];   // [16, 3, 32768] fp32
    float* out = (float*)d_out;                 // [16, 3, 2048] fp32
    ull* ws = (ull*)d_ws;                       // 16 x 640 words = 80 KB used
    void* args[] = { (void*)&pts, (void*)&out, (void*)&ws };
    hipLaunchCooperativeKernel((const void*)fps_kernel,
                               dim3(FPS_B * BLK_PER_B), dim3(FPS_T),
                               args, 0, stream);
}

// Round 17
// 1517.559 us; speedup vs baseline: 3.5026x; 1.0412x over previous
//
#include <hip/hip_runtime.h>

#define FPS_N 32768
#define FPS_M 2048
#define FPS_B 16
#define BLK_PER_B 8
#define FPS_T 576                 // 9 waves: wave 0 = comm, waves 1-8 = scan
#define SCT 512                   // scan threads
#define PTS (FPS_N / BLK_PER_B)   // 4096 points per block
#define PPT (PTS / SCT)           // 8 points per scan thread
#define KPUB 4                    // candidates published per wave
#define RING 128
#define WSTRIDE 640               // ws words per batch: 2 parities x 320

typedef unsigned long long ull;

// u64 max step via DPP (VALU pipe). old = self -> masked/invalid lanes
// return self (identity-safe). Verified correct rounds 11/15/16.
#define DPP_MAX_STEP(ctrl, rmask)                                              \
    {                                                                          \
        unsigned plo = (unsigned)__builtin_amdgcn_update_dpp(                  \
            (int)lo, (int)lo, (ctrl), (rmask), 0xf, false);                    \
        unsigned phi = (unsigned)__builtin_amdgcn_update_dpp(                  \
            (int)hi, (int)hi, (ctrl), (rmask), 0xf, false);                    \
        if (phi > hi || (phi == hi && plo > lo)) { hi = phi; lo = plo; }       \
    }

// wave max valid in lane 63, broadcast via readlane
__device__ __forceinline__ ull wave_max_u64(ull v) {
    unsigned lo = (unsigned)v, hi = (unsigned)(v >> 32);
    DPP_MAX_STEP(0x111, 0xf)      // row_shr:1
    DPP_MAX_STEP(0x112, 0xf)      // row_shr:2
    DPP_MAX_STEP(0x114, 0xf)      // row_shr:4
    DPP_MAX_STEP(0x118, 0xf)      // row_shr:8
    DPP_MAX_STEP(0x142, 0xa)      // row_bcast:15
    DPP_MAX_STEP(0x143, 0xc)      // row_bcast:31 -> lane 63
    unsigned blo = (unsigned)__builtin_amdgcn_readlane((int)lo, 63);
    unsigned bhi = (unsigned)__builtin_amdgcn_readlane((int)hi, 63);
    return ((ull)bhi << 32) | blo;
}

__device__ __forceinline__ float readlane_f(float v, int l) {
    return __uint_as_float(
        (unsigned)__builtin_amdgcn_readlane((int)__float_as_uint(v), l));
}

// EXACT LAZY-BATCHED FPS v5. Structure = round 15/16 (1.58 ms). Round-16
// post-mortem: sleep backoff was neutral -> VALU ~20% is REAL work; the
// epoch chain (~8.1k cyc) serializes B's 5 extraction rounds, then publish
// visibility, then a 12-word coord gather. Round-17 = PIPELINE, no protocol
// change:
//  (1) INCREMENTAL PUBLISH: lane r stores candidate word r right after
//      extraction round r (cut last) -> candidate LLC visibility overlaps
//      B's remaining rounds; only the cut word's visibility stays serial.
//      Word value is final at round end; parity-reuse proof unchanged
//      (publish of e still requires full apply of e-1 -> all comms done
//      reading e-2).
//  (2) IN-POLL COORD PREFETCH: comm fetches X/Y/Z[g] the moment a candidate
//      word is caught; loads fly during the residual poll (first use after
//      vcut) -> gather leaves the chain.
//  (3) final extraction round skips the mask step (result unused).
// Protocol recap: per-wave top-4 + 5th-as-cut, packed u64 =
// dist<<32|invidx<<17|tag (u64 order == np.argmax first-occurrence; dist>=0
// IEEE-bit monotone, inverted idx = lowest-index ties). Comm sims while
// pool max > vcutg (max of 64 wave-5ths; unpublished <= its wave's 5th;
// values only decrease), posts selections to LDS ring (monotone release
// tags); scan waves apply as posted, emit output rows. Zero steady-state
// barriers. Tags <= 2047 (12 bits; ws 0xAA poison field 0xAAA never
// matches). Numerics bit-exact: contract off, (dx*dx+dy*dy)+dz*dz, no fma.
__global__ __launch_bounds__(FPS_T)
__attribute__((amdgpu_waves_per_eu(1)))
void fps_kernel(const float* __restrict__ pts, float* __restrict__ out,
                ull* __restrict__ ws) {
#pragma clang fp contract(off)
    __shared__ float srx[RING], sry[RING], srz[RING];
    __shared__ unsigned rtag[RING];
    __shared__ unsigned etot;           // (epoch<<16) | last_posted_row

    const int blk = blockIdx.x;
    const int b = blk & 15;             // batch
    const int j = blk >> 4;             // block-within-batch 0..7
    const int tid = threadIdx.x;
    const int lane = tid & 63;
    const float* __restrict__ X = pts + (size_t)b * 3 * FPS_N;
    const float* __restrict__ Y = X + FPS_N;
    const float* __restrict__ Z = Y + FPS_N;
    const int off = j * PTS;
    float* __restrict__ outb = out + (size_t)b * 3 * FPS_M;
    ull* __restrict__ wsb = ws + (size_t)b * WSTRIDE;

    for (int q = tid; q < RING; q += FPS_T) rtag[q] = 0;
    if (tid == 0) etot = 0;
    __syncthreads();                    // only barrier (pre-loop)

    const float p0x = X[0], p0y = Y[0], p0z = Z[0];

    if (tid < 64) {
        // ================= comm wave =================
        if (j == 0 && lane == 0) {      // row 0 = point 0
            outb[0] = p0x; outb[FPS_M] = p0y; outb[2 * FPS_M] = p0z;
        }
        int last = 0;
        for (unsigned e = 1; last < FPS_M - 1; ++e) {
            ull* grp = wsb + (e & 1) * 320;
            // poll lane l = wave l: 4 cand words + 1 cut word; fetch coords
            // for each candidate AS CAUGHT (loads overlap residual poll)
            ull* ca = grp + lane * 4;
            ull* cu = grp + 256 + lane;
            ull cv[KPUB] = {0, 0, 0, 0};
            float ccx[KPUB] = {0, 0, 0, 0};
            float ccy[KPUB] = {0, 0, 0, 0};
            float ccz[KPUB] = {0, 0, 0, 0};
            bool kc0 = false, kc1 = false, kc2 = false, kc3 = false, kw = false;
            ull cw = 0;
            for (int it = 0; it < (1 << 25); ++it) {
#pragma unroll
                for (int c = 0; c < KPUB; ++c) {
                    bool& kc = (c == 0) ? kc0 : (c == 1) ? kc1 : (c == 2) ? kc2 : kc3;
                    if (!kc) {
                        ull v = __hip_atomic_load(ca + c, __ATOMIC_RELAXED,
                                                  __HIP_MEMORY_SCOPE_AGENT);
                        if ((unsigned)(v & 0xFFFull) == e) {
                            cv[c] = v;
                            kc = true;
                            const int g = 32767 - (int)((v >> 17) & 0x7FFFull);
                            ccx[c] = X[g];      // prefetch: in flight during poll
                            ccy[c] = Y[g];
                            ccz[c] = Z[g];
                        }
                    }
                }
                if (!kw) {
                    cw = __hip_atomic_load(cu, __ATOMIC_RELAXED,
                                           __HIP_MEMORY_SCOPE_AGENT);
                    kw = ((unsigned)(cw & 0xFFFull) == e);
                }
                if (__all(kc0 && kc1 && kc2 && kc3 && kw)) break;
                __builtin_amdgcn_s_sleep(1);    // miss: free the SIMD
            }
            const ull vcutg = wave_max_u64(cw);   // max of 64 wave-5ths
            int posted = 0;
            while (last < FPS_M - 1 && posted < RING) {
                ull m = cv[0];
#pragma unroll
                for (int c = 1; c < KPUB; ++c)
                    if (cv[c] > m) m = cv[c];
                const ull W = wave_max_u64(m);    // uniform in all lanes
                if (W <= vcutg) break;
                // winner lane + in-lane coord select (words globally unique)
                bool own = false;
                float sx = 0.0f, sy = 0.0f, sz = 0.0f;
#pragma unroll
                for (int c = 0; c < KPUB; ++c) {
                    const bool h = (cv[c] == W);
                    own |= h;
                    sx = h ? ccx[c] : sx;
                    sy = h ? ccy[c] : sy;
                    sz = h ? ccz[c] : sz;
                    cv[c] = h ? 0 : cv[c];        // consume
                }
                const ull mk = __ballot(own);     // exactly one bit
                const int wl = __ffsll((long long)mk) - 1;
                const float wx = readlane_f(sx, wl);
                const float wy = readlane_f(sy, wl);
                const float wz = readlane_f(sz, wl);
                // update pool (same IEEE ops as the batched apply)
#pragma unroll
                for (int c = 0; c < KPUB; ++c) {
                    float dx = ccx[c] - wx, dy = ccy[c] - wy, dz = ccz[c] - wz;
                    float d = (dx * dx + dy * dy) + dz * dz;
                    float df = __uint_as_float((unsigned)(cv[c] >> 32));
                    float nd = d < df ? d : df;   // consumed (0) stays 0
                    cv[c] = ((ull)__float_as_uint(nd) << 32)
                          | (cv[c] & 0xFFFFFFFFull);
                }
                ++last; ++posted;
                const int slot = last & (RING - 1);
                if (lane == 0) {                  // post to ring, release tag
                    srx[slot] = wx; sry[slot] = wy; srz[slot] = wz;
                    __hip_atomic_store(&rtag[slot], (unsigned)last,
                                       __ATOMIC_RELEASE,
                                       __HIP_MEMORY_SCOPE_WORKGROUP);
                }
            }
            if (lane == 0)
                __hip_atomic_store(&etot, (e << 16) | (unsigned)last,
                                   __ATOMIC_RELAXED, __HIP_MEMORY_SCOPE_WORKGROUP);
        }
    } else {
        // ================= scan waves =================
        const int st = tid - 64;        // 0..511
        const int w = (tid >> 6) - 1;   // scan wave 0..7
        const int wid = j * 8 + w;      // wave id within batch 0..63
        float cx[PPT], cy[PPT], cz[PPT], dist[PPT];
        unsigned inv[PPT];
#pragma unroll
        for (int k = 0; k < PPT; ++k) { // coords in regs; apply p0 inline
            const int g = off + k * SCT + st;
            cx[k] = X[g]; cy[k] = Y[g]; cz[k] = Z[g];
            float dx = cx[k] - p0x, dy = cy[k] - p0y, dz = cz[k] - p0z;
            dist[k] = (dx * dx + dy * dy) + dz * dz;
            inv[k] = 32767u - (unsigned)g;
        }
        unsigned applied = 0;
        for (unsigned e = 1;; ++e) {
            ull* grp = wsb + (e & 1) * 320;
            // B: 5 masked DPP extraction rounds; PUBLISH EACH ROUND'S WORD
            // IMMEDIATELY (candidate visibility overlaps later rounds; only
            // the cut word's visibility stays on the chain). Last round
            // skips masking (result unused after).
            ull pk[PPT];
#pragma unroll
            for (int k = 0; k < PPT; ++k)
                pk[k] = ((ull)__float_as_uint(dist[k]) << 32) | ((ull)inv[k] << 17);
#pragma unroll
            for (int r = 0; r < KPUB + 1; ++r) {
                ull m = pk[0];
#pragma unroll
                for (int k = 1; k < PPT; ++k)
                    if (pk[k] > m) m = pk[k];
                const ull W = wave_max_u64(m);
                if (r < KPUB) {
#pragma unroll
                    for (int k = 0; k < PPT; ++k)
                        if (pk[k] == W) pk[k] = 0;    // unique -> exact mask
                    if (lane == r)
                        __hip_atomic_store(grp + wid * 4 + r, W | (ull)e,
                                           __ATOMIC_RELAXED,
                                           __HIP_MEMORY_SCOPE_AGENT);
                } else {
                    if (lane == KPUB)
                        __hip_atomic_store(grp + 256 + wid, W | (ull)e,
                                           __ATOMIC_RELAXED,
                                           __HIP_MEMORY_SCOPE_AGENT);
                }
            }
            // apply: consume ring entries as posted; sleep when idle
            unsigned last_row = 0;
            bool have = false;
            for (;;) {
                bool did = false;
                if (!have) {
                    unsigned u = __hip_atomic_load(&etot, __ATOMIC_RELAXED,
                                                   __HIP_MEMORY_SCOPE_WORKGROUP);
                    if ((u >> 16) == e) { last_row = u & 0xFFFFu; have = true; did = true; }
                }
                const unsigned want = applied + 1;
                if (!have || want <= last_row) {
                    const int slot = (int)(want & (RING - 1));
                    if (__hip_atomic_load(&rtag[slot], __ATOMIC_ACQUIRE,
                                          __HIP_MEMORY_SCOPE_WORKGROUP) == want) {
                        const float wx = srx[slot], wy = sry[slot], wz = srz[slot];
#pragma unroll
                        for (int k = 0; k < PPT; ++k) {
                            float dx = cx[k] - wx, dy = cy[k] - wy, dz = cz[k] - wz;
                            float d = (dx * dx + dy * dy) + dz * dz;
                            dist[k] = d < dist[k] ? d : dist[k];
                        }
                        if (j == 0 && w == 0 && lane < 3) {   // emit row
                            float cvv = lane == 0 ? wx : (lane == 1 ? wy : wz);
                            outb[(size_t)lane * FPS_M + want] = cvv;
                        }
                        applied = want;
                        did = true;
                    }
                }
                if (have && applied == last_row) break;
                if (!did) __builtin_amdgcn_s_sleep(1);  // idle: free the SIMD
            }
            if (last_row >= FPS_M - 1) break;
        }
    }
}

extern "C" void kernel_launch(void* const* d_in, const int* in_sizes, int n_in,
                              void* d_out, int out_size, void* d_ws, size_t ws_size,
                              hipStream_t stream) {
    const float* pts = (const float*)d_in[0];   // [16, 3, 32768] fp32
    float* out = (float*)d_out;                 // [16, 3, 2048] fp32
    ull* ws = (ull*)d_ws;                       // 16 x 640 words = 80 KB used
    void* args[] = { (void*)&pts, (void*)&out, (void*)&ws };
    hipLaunchCooperativeKernel((const void*)fps_kernel,
                               dim3(FPS_B * BLK_PER_B), dim3(FPS_T),
                               args, 0, stream);
}

// Round 18
// 1497.591 us; speedup vs baseline: 3.5493x; 1.0133x over previous
//
#include <hip/hip_runtime.h>

#define FPS_N 32768
#define FPS_M 2048
#define FPS_B 16
#define BLK_PER_B 8
#define FPS_T 576                 // 9 waves: wave 0 = comm, waves 1-8 = scan
#define SCT 512                   // scan threads
#define PTS (FPS_N / BLK_PER_B)   // 4096 points per block
#define PPT (PTS / SCT)           // 8 points per scan thread
#define KPUB 4                    // candidates published per wave
#define RING 128
#define WSTRIDE 640               // ws words per batch: 2 parities x 320

typedef unsigned long long ull;

// u64 max step via DPP (identity-safe: old = self). Verified rounds 11/15-17.
#define DPP_MAX_STEP(ctrl, rmask)                                              \
    {                                                                          \
        unsigned plo = (unsigned)__builtin_amdgcn_update_dpp(                  \
            (int)lo, (int)lo, (ctrl), (rmask), 0xf, false);                    \
        unsigned phi = (unsigned)__builtin_amdgcn_update_dpp(                  \
            (int)hi, (int)hi, (ctrl), (rmask), 0xf, false);                    \
        if (phi > hi || (phi == hi && plo > lo)) { hi = phi; lo = plo; }       \
    }

__device__ __forceinline__ ull wave_max_u64(ull v) {
    unsigned lo = (unsigned)v, hi = (unsigned)(v >> 32);
    DPP_MAX_STEP(0x111, 0xf)
    DPP_MAX_STEP(0x112, 0xf)
    DPP_MAX_STEP(0x114, 0xf)
    DPP_MAX_STEP(0x118, 0xf)
    DPP_MAX_STEP(0x142, 0xa)
    DPP_MAX_STEP(0x143, 0xc)
    unsigned blo = (unsigned)__builtin_amdgcn_readlane((int)lo, 63);
    unsigned bhi = (unsigned)__builtin_amdgcn_readlane((int)hi, 63);
    return ((ull)bhi << 32) | blo;
}

// f32 wave max (exact: fp max is associative/commutative, no NaNs here),
// broadcast from lane 63. ~half the issue cost of the u64 version.
__device__ __forceinline__ float wave_max_f32(float v) {
    float mf = v;
#define DPP_FMAX_STEP(ctrl, rmask)                                             \
    {                                                                          \
        int p = __builtin_amdgcn_update_dpp(                                   \
            (int)__float_as_uint(mf), (int)__float_as_uint(mf), (ctrl),        \
            (rmask), 0xf, false);                                              \
        float pf = __uint_as_float((unsigned)p);                               \
        if (pf > mf) mf = pf;                                                  \
    }
    DPP_FMAX_STEP(0x111, 0xf)
    DPP_FMAX_STEP(0x112, 0xf)
    DPP_FMAX_STEP(0x114, 0xf)
    DPP_FMAX_STEP(0x118, 0xf)
    DPP_FMAX_STEP(0x142, 0xa)
    DPP_FMAX_STEP(0x143, 0xc)
    return __uint_as_float(
        (unsigned)__builtin_amdgcn_readlane((int)__float_as_uint(mf), 63));
}

// u32 wave min (identity-safe), broadcast from lane 63. Rare-tie path only.
__device__ __forceinline__ unsigned wave_min_u32(unsigned v) {
    unsigned m = v;
#define DPP_UMIN_STEP(ctrl, rmask)                                             \
    {                                                                          \
        unsigned p = (unsigned)__builtin_amdgcn_update_dpp(                    \
            (int)m, (int)m, (ctrl), (rmask), 0xf, false);                      \
        if (p < m) m = p;                                                      \
    }
    DPP_UMIN_STEP(0x111, 0xf)
    DPP_UMIN_STEP(0x112, 0xf)
    DPP_UMIN_STEP(0x114, 0xf)
    DPP_UMIN_STEP(0x118, 0xf)
    DPP_UMIN_STEP(0x142, 0xa)
    DPP_UMIN_STEP(0x143, 0xc)
    return (unsigned)__builtin_amdgcn_readlane((int)m, 63);
}

__device__ __forceinline__ float readlane_f(float v, int l) {
    return __uint_as_float(
        (unsigned)__builtin_amdgcn_readlane((int)__float_as_uint(v), l));
}

// EXACT LAZY-BATCHED FPS v6. Structure = round 17 (1.48 ms steady) with ONE
// change: the scan-wave B phase (top-5 extraction) runs on f32 dist max +
// EXACT lowest-global-index tie resolve instead of packed-u64 max:
//   round r: W = wave f32-max of remaining fd[] (7 fmax + 6-step DPP fmax);
//   each lane takes the smallest k with fd[k]==W (descending overwrite ->
//   lowest k = lowest global index, since g = off + k*SCT + st is increasing
//   in k and, for fixed k, in lane); ballot -> if one lane matches, dynamic
//   readlane; else (exact f32 dist tie across lanes, rare) DPP u32-min.
//   Published word rebuilt as dist<<32 | (32767-g)<<17 | tag == identical to
//   what the u64 extraction produced -> downstream unchanged, bit-exact.
//   Masking clears exactly the winner (match on g AND value); sentinel -1.0f
//   < every real dist (>= +0.0).
// Rationale (r17 post-mortem): chain ~4.0k cyc/epoch x ~890 epochs (t~2.3);
// B wall ~1.6k of it is u64-op issue x 2 scan waves/SIMD. f32 rounds are
// ~half the issue -> B wall ~0.85k. k-sweep modeled flat (t grows sublinearly
// with k while B+sim grow linearly), so k stays 4.
// Protocol (rounds 14-17): per-wave top-4 + 5th-as-cut published straight to
// LLC (relaxed agent, incremental per round, self-validating tags); comm
// wave polls 5 words/lane w/ in-poll coord prefetch, sims while pool max >
// vcutg (max of 64 wave-5ths bounds every unpublished point; values only
// decrease), posts selections to LDS ring (monotone release tags); scan
// waves apply as posted (overlaps sim), emit output rows. Zero steady-state
// barriers; s_sleep(1) on every spin miss. Parity reuse at e+2 / ring reuse
// at +128 provably post-consumption. Tags <= 2047 (12 bits; ws 0xAA poison
// field 0xAAA never matches). Numerics bit-exact: contract off,
// (dx*dx+dy*dy)+dz*dz, min via ?:, no fma.
__global__ __launch_bounds__(FPS_T)
__attribute__((amdgpu_waves_per_eu(1)))
void fps_kernel(const float* __restrict__ pts, float* __restrict__ out,
                ull* __restrict__ ws) {
#pragma clang fp contract(off)
    __shared__ float srx[RING], sry[RING], srz[RING];
    __shared__ unsigned rtag[RING];
    __shared__ unsigned etot;           // (epoch<<16) | last_posted_row

    const int blk = blockIdx.x;
    const int b = blk & 15;             // batch
    const int j = blk >> 4;             // block-within-batch 0..7
    const int tid = threadIdx.x;
    const int lane = tid & 63;
    const float* __restrict__ X = pts + (size_t)b * 3 * FPS_N;
    const float* __restrict__ Y = X + FPS_N;
    const float* __restrict__ Z = Y + FPS_N;
    const int off = j * PTS;
    float* __restrict__ outb = out + (size_t)b * 3 * FPS_M;
    ull* __restrict__ wsb = ws + (size_t)b * WSTRIDE;

    for (int q = tid; q < RING; q += FPS_T) rtag[q] = 0;
    if (tid == 0) etot = 0;
    __syncthreads();                    // only barrier (pre-loop)

    const float p0x = X[0], p0y = Y[0], p0z = Z[0];

    if (tid < 64) {
        // ================= comm wave =================
        if (j == 0 && lane == 0) {      // row 0 = point 0
            outb[0] = p0x; outb[FPS_M] = p0y; outb[2 * FPS_M] = p0z;
        }
        int last = 0;
        for (unsigned e = 1; last < FPS_M - 1; ++e) {
            ull* grp = wsb + (e & 1) * 320;
            // poll lane l = wave l: 4 cand words + 1 cut word; coords fetched
            // as each candidate is caught (loads overlap residual poll)
            ull* ca = grp + lane * 4;
            ull* cu = grp + 256 + lane;
            ull cv[KPUB] = {0, 0, 0, 0};
            float ccx[KPUB] = {0, 0, 0, 0};
            float ccy[KPUB] = {0, 0, 0, 0};
            float ccz[KPUB] = {0, 0, 0, 0};
            bool kc0 = false, kc1 = false, kc2 = false, kc3 = false, kw = false;
            ull cw = 0;
            for (int it = 0; it < (1 << 25); ++it) {
#pragma unroll
                for (int c = 0; c < KPUB; ++c) {
                    bool& kc = (c == 0) ? kc0 : (c == 1) ? kc1 : (c == 2) ? kc2 : kc3;
                    if (!kc) {
                        ull v = __hip_atomic_load(ca + c, __ATOMIC_RELAXED,
                                                  __HIP_MEMORY_SCOPE_AGENT);
                        if ((unsigned)(v & 0xFFFull) == e) {
                            cv[c] = v;
                            kc = true;
                            const int g = 32767 - (int)((v >> 17) & 0x7FFFull);
                            ccx[c] = X[g];      // prefetch during residual poll
                            ccy[c] = Y[g];
                            ccz[c] = Z[g];
                        }
                    }
                }
                if (!kw) {
                    cw = __hip_atomic_load(cu, __ATOMIC_RELAXED,
                                           __HIP_MEMORY_SCOPE_AGENT);
                    kw = ((unsigned)(cw & 0xFFFull) == e);
                }
                if (__all(kc0 && kc1 && kc2 && kc3 && kw)) break;
                __builtin_amdgcn_s_sleep(1);    // miss: free the SIMD
            }
            const ull vcutg = wave_max_u64(cw);   // max of 64 wave-5ths
            int posted = 0;
            while (last < FPS_M - 1 && posted < RING) {
                ull m = cv[0];
#pragma unroll
                for (int c = 1; c < KPUB; ++c)
                    if (cv[c] > m) m = cv[c];
                const ull W = wave_max_u64(m);    // uniform in all lanes
                if (W <= vcutg) break;
                bool own = false;
                float sx = 0.0f, sy = 0.0f, sz = 0.0f;
#pragma unroll
                for (int c = 0; c < KPUB; ++c) {
                    const bool h = (cv[c] == W);  // words globally unique
                    own |= h;
                    sx = h ? ccx[c] : sx;
                    sy = h ? ccy[c] : sy;
                    sz = h ? ccz[c] : sz;
                    cv[c] = h ? 0 : cv[c];        // consume
                }
                const ull mk = __ballot(own);     // exactly one bit
                const int wl = __ffsll((long long)mk) - 1;
                const float wx = readlane_f(sx, wl);
                const float wy = readlane_f(sy, wl);
                const float wz = readlane_f(sz, wl);
                // update pool (same IEEE ops as the batched apply)
#pragma unroll
                for (int c = 0; c < KPUB; ++c) {
                    float dx = ccx[c] - wx, dy = ccy[c] - wy, dz = ccz[c] - wz;
                    float d = (dx * dx + dy * dy) + dz * dz;
                    float df = __uint_as_float((unsigned)(cv[c] >> 32));
                    float nd = d < df ? d : df;   // consumed (0) stays 0
                    cv[c] = ((ull)__float_as_uint(nd) << 32)
                          | (cv[c] & 0xFFFFFFFFull);
                }
                ++last; ++posted;
                const int slot = last & (RING - 1);
                if (lane == 0) {                  // post to ring, release tag
                    srx[slot] = wx; sry[slot] = wy; srz[slot] = wz;
                    __hip_atomic_store(&rtag[slot], (unsigned)last,
                                       __ATOMIC_RELEASE,
                                       __HIP_MEMORY_SCOPE_WORKGROUP);
                }
            }
            if (lane == 0)
                __hip_atomic_store(&etot, (e << 16) | (unsigned)last,
                                   __ATOMIC_RELAXED, __HIP_MEMORY_SCOPE_WORKGROUP);
        }
    } else {
        // ================= scan waves =================
        const int st = tid - 64;        // 0..511
        const int w = (tid >> 6) - 1;   // scan wave 0..7
        const int wid = j * 8 + w;      // wave id within batch 0..63
        float cx[PPT], cy[PPT], cz[PPT], dist[PPT];
#pragma unroll
        for (int k = 0; k < PPT; ++k) { // coords in regs; apply p0 inline
            const int g = off + k * SCT + st;
            cx[k] = X[g]; cy[k] = Y[g]; cz[k] = Z[g];
            float dx = cx[k] - p0x, dy = cy[k] - p0y, dz = cz[k] - p0z;
            dist[k] = (dx * dx + dy * dy) + dz * dz;
        }
        const int goff = off + st;      // g(k) = goff + k*SCT, increasing in k
        unsigned applied = 0;
        for (unsigned e = 1;; ++e) {
            ull* grp = wsb + (e & 1) * 320;
            // ---- B: top-5 via f32 extraction + exact index tie resolve ----
            float fd[PPT];
#pragma unroll
            for (int k = 0; k < PPT; ++k) fd[k] = dist[k];
#pragma unroll
            for (int r = 0; r < KPUB + 1; ++r) {
                float m = fd[0];
#pragma unroll
                for (int k = 1; k < PPT; ++k) m = fmaxf(m, fd[k]);
                const float W = wave_max_f32(m);
                // lane-local lowest-index holder of W (descending overwrite)
                unsigned mg = 0xFFFFFFFFu;
#pragma unroll
                for (int k = PPT - 1; k >= 0; --k)
                    if (fd[k] == W) mg = (unsigned)(goff + k * SCT);
                const ull mk = __ballot(mg != 0xFFFFFFFFu);   // >= 1 bit
                unsigned gw;
                if (__popcll(mk) == 1) {          // unique holder (common)
                    gw = (unsigned)__builtin_amdgcn_readlane(
                        (int)mg, (int)(__ffsll((long long)mk) - 1));
                } else {                          // exact dist tie (rare)
                    gw = wave_min_u32(mg);
                }
                const ull word = ((ull)__float_as_uint(W) << 32)
                               | ((ull)(32767u - gw) << 17) | (ull)e;
                if (r < KPUB) {
#pragma unroll
                    for (int k = 0; k < PPT; ++k)  // mask exactly the winner
                        if ((unsigned)(goff + k * SCT) == gw && fd[k] == W)
                            fd[k] = -1.0f;         // < every real dist (>=+0)
                    if (lane == r)                 // incremental publish
                        __hip_atomic_store(grp + wid * 4 + r, word,
                                           __ATOMIC_RELAXED,
                                           __HIP_MEMORY_SCOPE_AGENT);
                } else {
                    if (lane == KPUB)              // the cut (5th best)
                        __hip_atomic_store(grp + 256 + wid, word,
                                           __ATOMIC_RELAXED,
                                           __HIP_MEMORY_SCOPE_AGENT);
                }
            }
            // ---- apply: consume ring entries as posted; sleep when idle ----
            unsigned last_row = 0;
            bool have = false;
            for (;;) {
                bool did = false;
                if (!have) {
                    unsigned u = __hip_atomic_load(&etot, __ATOMIC_RELAXED,
                                                   __HIP_MEMORY_SCOPE_WORKGROUP);
                    if ((u >> 16) == e) { last_row = u & 0xFFFFu; have = true; did = true; }
                }
                const unsigned want = applied + 1;
                if (!have || want <= last_row) {
                    const int slot = (int)(want & (RING - 1));
                    if (__hip_atomic_load(&rtag[slot], __ATOMIC_ACQUIRE,
                                          __HIP_MEMORY_SCOPE_WORKGROUP) == want) {
                        const float wx = srx[slot], wy = sry[slot], wz = srz[slot];
#pragma unroll
                        for (int k = 0; k < PPT; ++k) {
                            float dx = cx[k] - wx, dy = cy[k] - wy, dz = cz[k] - wz;
                            float d = (dx * dx + dy * dy) + dz * dz;
                            dist[k] = d < dist[k] ? d : dist[k];
                        }
                        if (j == 0 && w == 0 && lane < 3) {   // emit row
                            float cvv = lane == 0 ? wx : (lane == 1 ? wy : wz);
                            outb[(size_t)lane * FPS_M + want] = cvv;
                        }
                        applied = want;
                        did = true;
                    }
                }
                if (have && applied == last_row) break;
                if (!did) __builtin_amdgcn_s_sleep(1);  // idle: free the SIMD
            }
            if (last_row >= FPS_M - 1) break;
        }
    }
}

extern "C" void kernel_launch(void* const* d_in, const int* in_sizes, int n_in,
                              void* d_out, int out_size, void* d_ws, size_t ws_size,
                              hipStream_t stream) {
    const float* pts = (const float*)d_in[0];   // [16, 3, 32768] fp32
    float* out = (float*)d_out;                 // [16, 3, 2048] fp32
    ull* ws = (ull*)d_ws;                       // 16 x 640 words = 80 KB used
    void* args[] = { (void*)&pts, (void*)&out, (void*)&ws };
    hipLaunchCooperativeKernel((const void*)fps_kernel,
                               dim3(FPS_B * BLK_PER_B), dim3(FPS_T),
                               args, 0, stream);
}